// Round 3
// baseline (809.938 us; speedup 1.0000x reference)
//
#include <hip/hip_runtime.h>

// GraphSAGE 4×SAGEConv + MLP head, fp32 in/out.
// R3: coarse-bucket binning (128 dst-nodes/bucket) + per-bucket LDS fp32
// accumulation with bf16 messages. No fine-grained global scatter anywhere:
// the only 4B-random-write pattern (R2's fill_kernel, 107 MB HBM write-through)
// is replaced by LDS-sorted, bucket-contiguous flushes.

#define SH     7
#define BWID   128            // nodes per bucket  (requires n <= 1<<17 for packing)
#define NBMAX  1024
#define CHUNK  4096
#define EPT    (CHUNK / 256)  // edges per thread in binning kernels

__device__ __forceinline__ float silu_f(float v) { return v / (1.0f + __expf(-v)); }

__device__ __forceinline__ float bf_lo(unsigned u) { return __uint_as_float(u << 16); }
__device__ __forceinline__ float bf_hi(unsigned u) { return __uint_as_float(u & 0xFFFF0000u); }
__device__ __forceinline__ unsigned short f2bf(float f) {   // RNE
    unsigned x = __float_as_uint(f);
    unsigned r = x + 0x7FFFu + ((x >> 16) & 1u);
    return (unsigned short)(r >> 16);
}
__device__ __forceinline__ unsigned pack_bf2(float a, float b) {
    return (unsigned)f2bf(a) | ((unsigned)f2bf(b) << 16);
}

// ---------------- bucket CSR build ----------------

__global__ __launch_bounds__(256) void bucket_hist(
    const int* __restrict__ dst, int* __restrict__ bcnt, int ne)
{
    __shared__ int sh[NBMAX];
    const int t = threadIdx.x;
    for (int i = t; i < NBMAX; i += 256) sh[i] = 0;
    __syncthreads();
    const int base = blockIdx.x * CHUNK;
    for (int i = t; i < CHUNK; i += 256) {
        const int e = base + i;
        if (e < ne) atomicAdd(&sh[dst[e] >> SH], 1);
    }
    __syncthreads();
    for (int b = t; b < NBMAX; b += 256) {
        const int c = sh[b];
        if (c) atomicAdd(&bcnt[b], c);
    }
}

__global__ __launch_bounds__(1024) void bucket_scan(
    const int* __restrict__ bcnt, int* __restrict__ bbase,
    int* __restrict__ cursors, int nbuck, int ne)
{
    __shared__ int sh[NBMAX];
    const int t = threadIdx.x;
    const int c = (t < nbuck) ? bcnt[t] : 0;
    sh[t] = c;
    __syncthreads();
    int v = c;
    for (int off = 1; off < NBMAX; off <<= 1) {
        const int add = (t >= off) ? sh[t - off] : 0;
        __syncthreads();
        v += add;
        sh[t] = v;
        __syncthreads();
    }
    const int excl = v - c;
    if (t < nbuck) { bbase[t] = excl; cursors[t] = excl; }
    if (t == 0) bbase[nbuck] = ne;
}

// sort a CHUNK of edges by bucket in LDS, flush bucket-contiguous runs
__global__ __launch_bounds__(256) void bin_kernel(
    const int* __restrict__ src, const int* __restrict__ dst,
    int* __restrict__ cursors, unsigned* __restrict__ binned, int ne)
{
    __shared__ int   s_hist[NBMAX];
    __shared__ int   s_scan[NBMAX];
    __shared__ int   s_gbase[NBMAX];
    __shared__ int   s_p[256];
    __shared__ uint2 s_items[CHUNK];   // (bucket, packed)

    const int t = threadIdx.x;
    const int base = blockIdx.x * CHUNK;
    const int cnt = min(CHUNK, ne - base);

    int es[EPT], ed[EPT];
#pragma unroll
    for (int j = 0; j < EPT; ++j) {
        const int i = t + j * 256;
        if (i < cnt) { es[j] = src[base + i]; ed[j] = dst[base + i]; }
        else         { es[j] = -1; ed[j] = -1; }
    }

    for (int i = t; i < NBMAX; i += 256) s_hist[i] = 0;
    __syncthreads();
#pragma unroll
    for (int j = 0; j < EPT; ++j)
        if (es[j] >= 0) atomicAdd(&s_hist[ed[j] >> SH], 1);
    __syncthreads();

    // exclusive scan of NBMAX counters (4 per thread + block scan)
    const int l0 = s_hist[4 * t], l1 = s_hist[4 * t + 1];
    const int l2 = s_hist[4 * t + 2], l3 = s_hist[4 * t + 3];
    const int psum = l0 + l1 + l2 + l3;
    s_p[t] = psum;
    __syncthreads();
    int v = psum;
    for (int off = 1; off < 256; off <<= 1) {
        const int add = (t >= off) ? s_p[t - off] : 0;
        __syncthreads();
        v += add;
        s_p[t] = v;
        __syncthreads();
    }
    const int ex = v - psum;
    s_scan[4 * t] = ex;
    s_scan[4 * t + 1] = ex + l0;
    s_scan[4 * t + 2] = ex + l0 + l1;
    s_scan[4 * t + 3] = ex + l0 + l1 + l2;
    __syncthreads();

    // reserve contiguous global space: one atomic per (block,bucket)
    for (int b = t; b < NBMAX; b += 256) {
        const int c = s_hist[b];
        s_gbase[b] = c ? atomicAdd(&cursors[b], c) : 0;
    }
    __syncthreads();
    for (int i = t; i < NBMAX; i += 256) s_hist[i] = 0;   // reuse as cursor
    __syncthreads();

#pragma unroll
    for (int j = 0; j < EPT; ++j) {
        if (es[j] >= 0) {
            const int b  = ed[j] >> SH;
            const int ld = ed[j] & (BWID - 1);
            const int r  = atomicAdd(&s_hist[b], 1);
            s_items[s_scan[b] + r] = make_uint2((unsigned)b,
                                                ((unsigned)ld << 17) | (unsigned)es[j]);
        }
    }
    __syncthreads();

    for (int i = t; i < cnt; i += 256) {
        const uint2 it = s_items[i];
        const int b = (int)it.x;
        binned[s_gbase[b] + (i - s_scan[b])] = it.y;
    }
}

// ---------------- layers ----------------

// one block per bucket: LDS fp32 accumulator, edge-parallel bf16 gather
__global__ __launch_bounds__(256) void sage_agg(
    const int* __restrict__ bbase, const unsigned* __restrict__ binned,
    const unsigned* __restrict__ hlb,    // bf16x2 packed, [n*8] u32
    float* __restrict__ acc, int n)
{
    __shared__ float s_acc[BWID * 17];   // stride 17: spread ds_add banks
    const int b = blockIdx.x;
    const int t = threadIdx.x;
    const int n0 = b << SH;
    const int nn = min(BWID, n - n0);

    for (int i = t; i < nn * 16; i += 256) {
        const int ld = i >> 4, c = i & 15;
        s_acc[ld * 17 + c] = acc[(size_t)(n0 + ld) * 16 + c];
    }
    __syncthreads();

    const int beg = bbase[b], end = bbase[b + 1];
    const int q = t & 3;
    for (int k = beg + (t >> 2); k < end; k += 64) {
        const unsigned p = binned[k];
        const int ld = (int)(p >> 17);
        const int s  = (int)(p & 0x1FFFFu);
        const uint2 m = *(const uint2*)(hlb + (size_t)s * 8 + q * 2);
        float* a = &s_acc[ld * 17 + q * 4];
        atomicAdd(a + 0, bf_lo(m.x));
        atomicAdd(a + 1, bf_hi(m.x));
        atomicAdd(a + 2, bf_lo(m.y));
        atomicAdd(a + 3, bf_hi(m.y));
    }
    __syncthreads();

    for (int i = t; i < nn * 16; i += 256) {
        const int ld = i >> 4, c = i & 15;
        acc[(size_t)(n0 + ld) * 16 + c] = s_acc[ld * 17 + c];
    }
}

template <int DIN_, bool SILU_IN>
__global__ __launch_bounds__(256) void sage_dense(
    const float* __restrict__ hin,   // [n, DIN_] (pre-activation if SILU_IN)
    const float* __restrict__ Wl,    // [16, DIN_]
    const float* __restrict__ bl,    // [16]
    const float* __restrict__ Wr,    // [16, DIN_]
    unsigned* __restrict__ hlb,      // out: bf16(Wl * act(hin)) packed [n*8]
    float* __restrict__ acc,         // out: [n,16] = bl + Wr * act(hin)
    int n)
{
    __shared__ float sWl[16 * DIN_];
    __shared__ float sWr[16 * DIN_];
    __shared__ float sbl[16];

    const int t = threadIdx.x;
    for (int i = t; i < 16 * DIN_; i += 256) { sWl[i] = Wl[i]; sWr[i] = Wr[i]; }
    if (t < 16) sbl[t] = bl[t];
    __syncthreads();

    const int node = blockIdx.x * 256 + t;
    if (node >= n) return;

    float h[DIN_];
    const float4* __restrict__ xp = (const float4*)(hin + (size_t)node * DIN_);
#pragma unroll
    for (int q = 0; q < DIN_ / 4; ++q) {
        const float4 v = xp[q];
        h[q * 4 + 0] = v.x; h[q * 4 + 1] = v.y;
        h[q * 4 + 2] = v.z; h[q * 4 + 3] = v.w;
    }
    if (SILU_IN) {
#pragma unroll
        for (int d = 0; d < DIN_; ++d) h[d] = silu_f(h[d]);
    }

    float ol[16], oa[16];
#pragma unroll
    for (int j = 0; j < 16; ++j) {
        float al = 0.0f, ar = 0.0f;
#pragma unroll
        for (int d = 0; d < DIN_; ++d) {
            al = fmaf(sWl[j * DIN_ + d], h[d], al);
            ar = fmaf(sWr[j * DIN_ + d], h[d], ar);
        }
        ol[j] = al;
        oa[j] = sbl[j] + ar;
    }

    unsigned u[8];
#pragma unroll
    for (int q = 0; q < 8; ++q) u[q] = pack_bf2(ol[2 * q], ol[2 * q + 1]);
    uint4* __restrict__ hp = (uint4*)(hlb + (size_t)node * 8);
    hp[0] = make_uint4(u[0], u[1], u[2], u[3]);
    hp[1] = make_uint4(u[4], u[5], u[6], u[7]);

    float4* __restrict__ ap = (float4*)(acc + (size_t)node * 16);
#pragma unroll
    for (int q = 0; q < 4; ++q)
        ap[q] = make_float4(oa[q * 4], oa[q * 4 + 1], oa[q * 4 + 2], oa[q * 4 + 3]);
}

__global__ __launch_bounds__(256) void final_mlp(
    const float* __restrict__ accin,
    const float* __restrict__ W1, const float* __restrict__ b1,
    const float* __restrict__ W2, const float* __restrict__ b2,
    const float* __restrict__ W3, const float* __restrict__ b3,
    float* __restrict__ out, int n)
{
    __shared__ float sW1[32 * 16];
    __shared__ float sW2[32 * 32];
    __shared__ float sb1[32], sb2[32], sW3[32];
    __shared__ float sb3;

    const int t = threadIdx.x;
    for (int i = t; i < 32 * 16; i += 256) sW1[i] = W1[i];
    for (int i = t; i < 32 * 32; i += 256) sW2[i] = W2[i];
    if (t < 32) { sb1[t] = b1[t]; sb2[t] = b2[t]; sW3[t] = W3[t]; }
    if (t == 0) sb3 = b3[0];
    __syncthreads();

    const int node = blockIdx.x * 256 + t;
    if (node >= n) return;

    float h[16];
    const float4* __restrict__ xp = (const float4*)(accin + (size_t)node * 16);
#pragma unroll
    for (int q = 0; q < 4; ++q) {
        const float4 v = xp[q];
        h[q * 4 + 0] = silu_f(v.x); h[q * 4 + 1] = silu_f(v.y);
        h[q * 4 + 2] = silu_f(v.z); h[q * 4 + 3] = silu_f(v.w);
    }

    float a1[32];
#pragma unroll
    for (int j = 0; j < 32; ++j) {
        float s = sb1[j];
#pragma unroll
        for (int d = 0; d < 16; ++d) s = fmaf(sW1[j * 16 + d], h[d], s);
        a1[j] = silu_f(s);
    }

    float o = sb3;
#pragma unroll
    for (int j = 0; j < 32; ++j) {
        float s = sb2[j];
#pragma unroll
        for (int d = 0; d < 32; ++d) s = fmaf(sW2[j * 32 + d], a1[d], s);
        o = fmaf(sW3[j], silu_f(s), o);
    }
    out[node] = o;
}

extern "C" void kernel_launch(void* const* d_in, const int* in_sizes, int n_in,
                              void* d_out, int out_size, void* d_ws, size_t ws_size,
                              hipStream_t stream)
{
    const float* x   = (const float*)d_in[0];
    const int*   ei  = (const int*)d_in[1];
    const float* Wl0 = (const float*)d_in[2];
    const float* bl0 = (const float*)d_in[3];
    const float* Wr0 = (const float*)d_in[4];
    const float* Wls = (const float*)d_in[5];
    const float* bls = (const float*)d_in[6];
    const float* Wrs = (const float*)d_in[7];
    const float* W1  = (const float*)d_in[8];
    const float* b1  = (const float*)d_in[9];
    const float* W2  = (const float*)d_in[10];
    const float* b2  = (const float*)d_in[11];
    const float* W3  = (const float*)d_in[12];
    const float* b3  = (const float*)d_in[13];

    const int n  = in_sizes[0] / 32;
    const int ne = in_sizes[1] / 2;
    const int* src = ei;
    const int* dst = ei + ne;
    const int nbuck = (n + BWID - 1) >> SH;

    // workspace carve-up
    float*    acc0   = (float*)d_ws;                       // [n,16]
    float*    acc1   = acc0 + (size_t)n * 16;              // [n,16]
    unsigned* hlb    = (unsigned*)(acc1 + (size_t)n * 16); // [n*8]
    unsigned* binned = hlb + (size_t)n * 8;                // [ne]
    int*      bcnt   = (int*)(binned + (size_t)ne);        // [NBMAX]
    int*      bbase  = bcnt + NBMAX;                       // [NBMAX+1]
    int*      cursors= bbase + NBMAX + 1;                  // [NBMAX]

    const int nb  = (n + 255) / 256;
    const int cb  = (ne + CHUNK - 1) / CHUNK;

    // ---- bucket build ----
    hipMemsetAsync(bcnt, 0, NBMAX * sizeof(int), stream);
    bucket_hist<<<cb, 256, 0, stream>>>(dst, bcnt, ne);
    bucket_scan<<<1, 1024, 0, stream>>>(bcnt, bbase, cursors, nbuck, ne);
    bin_kernel<<<cb, 256, 0, stream>>>(src, dst, cursors, binned, ne);

    // ---- layers ----
    sage_dense<32, false><<<nb, 256, 0, stream>>>(x, Wl0, bl0, Wr0, hlb, acc0, n);
    sage_agg<<<nbuck, 256, 0, stream>>>(bbase, binned, hlb, acc0, n);

    sage_dense<16, true><<<nb, 256, 0, stream>>>(acc0, Wls + 0,   bls + 0,  Wrs + 0,   hlb, acc1, n);
    sage_agg<<<nbuck, 256, 0, stream>>>(bbase, binned, hlb, acc1, n);

    sage_dense<16, true><<<nb, 256, 0, stream>>>(acc1, Wls + 256, bls + 16, Wrs + 256, hlb, acc0, n);
    sage_agg<<<nbuck, 256, 0, stream>>>(bbase, binned, hlb, acc0, n);

    sage_dense<16, true><<<nb, 256, 0, stream>>>(acc0, Wls + 512, bls + 32, Wrs + 512, hlb, acc1, n);
    sage_agg<<<nbuck, 256, 0, stream>>>(bbase, binned, hlb, acc1, n);

    final_mlp<<<nb, 256, 0, stream>>>(acc1, W1, b1, W2, b2, W3, b3, (float*)d_out, n);
}

// Round 4
// 233.706 us; speedup vs baseline: 3.4656x; 3.4656x over previous
//
#include <hip/hip_runtime.h>

// GraphSAGE 4×SAGEConv + MLP head, fp32 in/out.
// R4: two-level binning (coarse buckets -> per-bucket LDS counting sort) gives
// a fully dst-sorted edge list + per-node CSR with only block-local writes.
// Per-layer aggregation is then an atomic-free gather: 2 lanes/node, uint4
// (8×bf16) loads from a 3.2 MB message array that is L2-resident per XCD.
// (R3's LDS float atomics: 100K bank conflicts, 175 us/layer -> gone.)

#define SH     7
#define BWID   128            // nodes per bucket (n <= 1<<17 for packing)
#define NBMAX  1024
#define CHUNK  4096
#define EPT    (CHUNK / 256)

__device__ __forceinline__ float silu_f(float v) { return v / (1.0f + __expf(-v)); }

__device__ __forceinline__ float bf_lo(unsigned u) { return __uint_as_float(u << 16); }
__device__ __forceinline__ float bf_hi(unsigned u) { return __uint_as_float(u & 0xFFFF0000u); }
__device__ __forceinline__ unsigned short f2bf(float f) {   // RNE
    unsigned x = __float_as_uint(f);
    unsigned r = x + 0x7FFFu + ((x >> 16) & 1u);
    return (unsigned short)(r >> 16);
}
__device__ __forceinline__ unsigned pack_bf2(float a, float b) {
    return (unsigned)f2bf(a) | ((unsigned)f2bf(b) << 16);
}

// ---------------- build ----------------

__global__ __launch_bounds__(256) void bucket_hist(
    const int* __restrict__ dst, int* __restrict__ bcnt, int ne)
{
    __shared__ int sh[NBMAX];
    const int t = threadIdx.x;
    for (int i = t; i < NBMAX; i += 256) sh[i] = 0;
    __syncthreads();
    const int base = blockIdx.x * CHUNK;
    for (int i = t; i < CHUNK; i += 256) {
        const int e = base + i;
        if (e < ne) atomicAdd(&sh[dst[e] >> SH], 1);
    }
    __syncthreads();
    for (int b = t; b < NBMAX; b += 256) {
        const int c = sh[b];
        if (c) atomicAdd(&bcnt[b], c);
    }
}

__global__ __launch_bounds__(1024) void bucket_scan(
    const int* __restrict__ bcnt, int* __restrict__ bbase,
    int* __restrict__ cursors, int* __restrict__ noff, int nbuck, int n, int ne)
{
    __shared__ int sh[NBMAX];
    const int t = threadIdx.x;
    const int c = (t < nbuck) ? bcnt[t] : 0;
    sh[t] = c;
    __syncthreads();
    int v = c;
    for (int off = 1; off < NBMAX; off <<= 1) {
        const int add = (t >= off) ? sh[t - off] : 0;
        __syncthreads();
        v += add;
        sh[t] = v;
        __syncthreads();
    }
    const int excl = v - c;
    if (t < nbuck) { bbase[t] = excl; cursors[t] = excl; }
    if (t == 0) { bbase[nbuck] = ne; noff[n] = ne; }
}

// sort a CHUNK of edges by bucket in LDS, flush bucket-contiguous runs
__global__ __launch_bounds__(256) void bin_kernel(
    const int* __restrict__ src, const int* __restrict__ dst,
    int* __restrict__ cursors, unsigned* __restrict__ binned0, int ne)
{
    __shared__ int   s_hist[NBMAX];
    __shared__ int   s_scan[NBMAX];
    __shared__ int   s_gbase[NBMAX];
    __shared__ int   s_p[256];
    __shared__ uint2 s_items[CHUNK];

    const int t = threadIdx.x;
    const int base = blockIdx.x * CHUNK;
    const int cnt = min(CHUNK, ne - base);

    int es[EPT], ed[EPT];
#pragma unroll
    for (int j = 0; j < EPT; ++j) {
        const int i = t + j * 256;
        if (i < cnt) { es[j] = src[base + i]; ed[j] = dst[base + i]; }
        else         { es[j] = -1; ed[j] = -1; }
    }

    for (int i = t; i < NBMAX; i += 256) s_hist[i] = 0;
    __syncthreads();
#pragma unroll
    for (int j = 0; j < EPT; ++j)
        if (es[j] >= 0) atomicAdd(&s_hist[ed[j] >> SH], 1);
    __syncthreads();

    const int l0 = s_hist[4 * t], l1 = s_hist[4 * t + 1];
    const int l2 = s_hist[4 * t + 2], l3 = s_hist[4 * t + 3];
    const int psum = l0 + l1 + l2 + l3;
    s_p[t] = psum;
    __syncthreads();
    int v = psum;
    for (int off = 1; off < 256; off <<= 1) {
        const int add = (t >= off) ? s_p[t - off] : 0;
        __syncthreads();
        v += add;
        s_p[t] = v;
        __syncthreads();
    }
    const int ex = v - psum;
    s_scan[4 * t] = ex;
    s_scan[4 * t + 1] = ex + l0;
    s_scan[4 * t + 2] = ex + l0 + l1;
    s_scan[4 * t + 3] = ex + l0 + l1 + l2;
    __syncthreads();

    for (int b = t; b < NBMAX; b += 256) {
        const int c = s_hist[b];
        s_gbase[b] = c ? atomicAdd(&cursors[b], c) : 0;
    }
    __syncthreads();
    for (int i = t; i < NBMAX; i += 256) s_hist[i] = 0;
    __syncthreads();

#pragma unroll
    for (int j = 0; j < EPT; ++j) {
        if (es[j] >= 0) {
            const int b  = ed[j] >> SH;
            const int ld = ed[j] & (BWID - 1);
            const int r  = atomicAdd(&s_hist[b], 1);
            s_items[s_scan[b] + r] = make_uint2((unsigned)b,
                                                ((unsigned)ld << 17) | (unsigned)es[j]);
        }
    }
    __syncthreads();

    for (int i = t; i < cnt; i += 256) {
        const uint2 it = s_items[i];
        const int b = (int)it.x;
        binned0[s_gbase[b] + (i - s_scan[b])] = it.y;
    }
}

// per-bucket LDS counting sort by local dst -> per-node-sorted src list + CSR
__global__ __launch_bounds__(256) void node_sort(
    const unsigned* __restrict__ binned0, const int* __restrict__ bbase,
    int* __restrict__ binned1, int* __restrict__ noff, int n)
{
    __shared__ int cnt[BWID];
    __shared__ int off_[BWID];
    const int b = blockIdx.x, t = threadIdx.x;
    const int beg = bbase[b], end = bbase[b + 1];

    if (t < BWID) cnt[t] = 0;
    __syncthreads();
    for (int k = beg + t; k < end; k += 256)
        atomicAdd(&cnt[binned0[k] >> 17], 1);
    __syncthreads();

    // exclusive scan of 128 counters (Hillis-Steele, t<128 active)
    if (t < BWID) off_[t] = cnt[t];
    __syncthreads();
    for (int o = 1; o < BWID; o <<= 1) {
        const int add = (t < BWID && t >= o) ? off_[t - o] : 0;
        __syncthreads();
        if (t < BWID) off_[t] += add;
        __syncthreads();
    }
    if (t < BWID) off_[t] -= cnt[t];   // inclusive -> exclusive
    __syncthreads();

    if (t < BWID) {
        const int node = (b << SH) + t;
        if (node <= n) noff[node] = beg + off_[t];
        cnt[t] = 0;                    // reuse as cursor
    }
    __syncthreads();

    for (int k = beg + t; k < end; k += 256) {
        const unsigned u = binned0[k];
        const int ld = (int)(u >> 17);
        const int r = atomicAdd(&cnt[ld], 1);
        binned1[beg + off_[ld] + r] = (int)(u & 0x1FFFFu);
    }
}

// ---------------- layers ----------------

// atomic-free gather: 2 lanes/node, each lane sums one uint4 (8 bf16) slice
__global__ __launch_bounds__(256) void sage_agg(
    const int* __restrict__ noff, const int* __restrict__ binned1,
    const unsigned* __restrict__ hlb, float* __restrict__ acc, int n)
{
    const int tid = blockIdx.x * 256 + threadIdx.x;
    const int node = tid >> 1;
    if (node >= n) return;
    const int q = tid & 1;
    const int beg = noff[node], end = noff[node + 1];

    const uint4* __restrict__ h4 = (const uint4*)hlb;  // [n*2]
    float s[8] = {0.f, 0.f, 0.f, 0.f, 0.f, 0.f, 0.f, 0.f};
    for (int k = beg; k < end; ++k) {
        const int sN = binned1[k];
        const uint4 m = h4[(size_t)sN * 2 + q];
        s[0] += bf_lo(m.x); s[1] += bf_hi(m.x);
        s[2] += bf_lo(m.y); s[3] += bf_hi(m.y);
        s[4] += bf_lo(m.z); s[5] += bf_hi(m.z);
        s[6] += bf_lo(m.w); s[7] += bf_hi(m.w);
    }
    float4* __restrict__ a4 = (float4*)acc;
    float4 a = a4[(size_t)node * 4 + 2 * q];
    a.x += s[0]; a.y += s[1]; a.z += s[2]; a.w += s[3];
    a4[(size_t)node * 4 + 2 * q] = a;
    float4 c = a4[(size_t)node * 4 + 2 * q + 1];
    c.x += s[4]; c.y += s[5]; c.z += s[6]; c.w += s[7];
    a4[(size_t)node * 4 + 2 * q + 1] = c;
}

template <int DIN_, bool SILU_IN>
__global__ __launch_bounds__(256) void sage_dense(
    const float* __restrict__ hin,
    const float* __restrict__ Wl, const float* __restrict__ bl,
    const float* __restrict__ Wr,
    unsigned* __restrict__ hlb,      // out: bf16(Wl * act(hin)) packed [n*8]
    float* __restrict__ acc,         // out: [n,16] = bl + Wr * act(hin)
    int n)
{
    __shared__ float sWl[16 * DIN_];
    __shared__ float sWr[16 * DIN_];
    __shared__ float sbl[16];

    const int t = threadIdx.x;
    for (int i = t; i < 16 * DIN_; i += 256) { sWl[i] = Wl[i]; sWr[i] = Wr[i]; }
    if (t < 16) sbl[t] = bl[t];
    __syncthreads();

    const int node = blockIdx.x * 256 + t;
    if (node >= n) return;

    float h[DIN_];
    const float4* __restrict__ xp = (const float4*)(hin + (size_t)node * DIN_);
#pragma unroll
    for (int q = 0; q < DIN_ / 4; ++q) {
        const float4 v = xp[q];
        h[q * 4 + 0] = v.x; h[q * 4 + 1] = v.y;
        h[q * 4 + 2] = v.z; h[q * 4 + 3] = v.w;
    }
    if (SILU_IN) {
#pragma unroll
        for (int d = 0; d < DIN_; ++d) h[d] = silu_f(h[d]);
    }

    float ol[16], oa[16];
#pragma unroll
    for (int j = 0; j < 16; ++j) {
        float al = 0.0f, ar = 0.0f;
#pragma unroll
        for (int d = 0; d < DIN_; ++d) {
            al = fmaf(sWl[j * DIN_ + d], h[d], al);
            ar = fmaf(sWr[j * DIN_ + d], h[d], ar);
        }
        ol[j] = al;
        oa[j] = sbl[j] + ar;
    }

    unsigned u[8];
#pragma unroll
    for (int q = 0; q < 8; ++q) u[q] = pack_bf2(ol[2 * q], ol[2 * q + 1]);
    uint4* __restrict__ hp = (uint4*)(hlb + (size_t)node * 8);
    hp[0] = make_uint4(u[0], u[1], u[2], u[3]);
    hp[1] = make_uint4(u[4], u[5], u[6], u[7]);

    float4* __restrict__ ap = (float4*)(acc + (size_t)node * 16);
#pragma unroll
    for (int q = 0; q < 4; ++q)
        ap[q] = make_float4(oa[q * 4], oa[q * 4 + 1], oa[q * 4 + 2], oa[q * 4 + 3]);
}

__global__ __launch_bounds__(256) void final_mlp(
    const float* __restrict__ accin,
    const float* __restrict__ W1, const float* __restrict__ b1,
    const float* __restrict__ W2, const float* __restrict__ b2,
    const float* __restrict__ W3, const float* __restrict__ b3,
    float* __restrict__ out, int n)
{
    __shared__ float sW1[32 * 16];
    __shared__ float sW2[32 * 32];
    __shared__ float sb1[32], sb2[32], sW3[32];
    __shared__ float sb3;

    const int t = threadIdx.x;
    for (int i = t; i < 32 * 16; i += 256) sW1[i] = W1[i];
    for (int i = t; i < 32 * 32; i += 256) sW2[i] = W2[i];
    if (t < 32) { sb1[t] = b1[t]; sb2[t] = b2[t]; sW3[t] = W3[t]; }
    if (t == 0) sb3 = b3[0];
    __syncthreads();

    const int node = blockIdx.x * 256 + t;
    if (node >= n) return;

    float h[16];
    const float4* __restrict__ xp = (const float4*)(accin + (size_t)node * 16);
#pragma unroll
    for (int q = 0; q < 4; ++q) {
        const float4 v = xp[q];
        h[q * 4 + 0] = silu_f(v.x); h[q * 4 + 1] = silu_f(v.y);
        h[q * 4 + 2] = silu_f(v.z); h[q * 4 + 3] = silu_f(v.w);
    }

    float a1[32];
#pragma unroll
    for (int j = 0; j < 32; ++j) {
        float s = sb1[j];
#pragma unroll
        for (int d = 0; d < 16; ++d) s = fmaf(sW1[j * 16 + d], h[d], s);
        a1[j] = silu_f(s);
    }

    float o = sb3;
#pragma unroll
    for (int j = 0; j < 32; ++j) {
        float s = sb2[j];
#pragma unroll
        for (int d = 0; d < 32; ++d) s = fmaf(sW2[j * 32 + d], a1[d], s);
        o = fmaf(sW3[j], silu_f(s), o);
    }
    out[node] = o;
}

extern "C" void kernel_launch(void* const* d_in, const int* in_sizes, int n_in,
                              void* d_out, int out_size, void* d_ws, size_t ws_size,
                              hipStream_t stream)
{
    const float* x   = (const float*)d_in[0];
    const int*   ei  = (const int*)d_in[1];
    const float* Wl0 = (const float*)d_in[2];
    const float* bl0 = (const float*)d_in[3];
    const float* Wr0 = (const float*)d_in[4];
    const float* Wls = (const float*)d_in[5];
    const float* bls = (const float*)d_in[6];
    const float* Wrs = (const float*)d_in[7];
    const float* W1  = (const float*)d_in[8];
    const float* b1  = (const float*)d_in[9];
    const float* W2  = (const float*)d_in[10];
    const float* b2  = (const float*)d_in[11];
    const float* W3  = (const float*)d_in[12];
    const float* b3  = (const float*)d_in[13];

    const int n  = in_sizes[0] / 32;
    const int ne = in_sizes[1] / 2;
    const int* src = ei;
    const int* dst = ei + ne;
    const int nbuck = (n + BWID - 1) >> SH;

    // workspace carve-up (~26 MB); hlb aliases binned0 (dead after node_sort)
    float*    acc0    = (float*)d_ws;                        // [n*16]
    float*    acc1    = acc0 + (size_t)n * 16;               // [n*16]
    int*      binned1 = (int*)(acc1 + (size_t)n * 16);       // [ne]
    int*      noff    = binned1 + (size_t)ne;                // [n+1]
    int*      bcnt    = noff + (n + 1);                      // [NBMAX]
    int*      bbase   = bcnt + NBMAX;                        // [NBMAX+1]
    int*      cursors = bbase + NBMAX + 1;                   // [NBMAX]
    unsigned* binned0 = (unsigned*)(cursors + NBMAX);        // [ne]
    unsigned* hlb     = binned0;                             // [n*8] alias

    const int nb = (n + 255) / 256;
    const int cb = (ne + CHUNK - 1) / CHUNK;
    const int ab = (n * 2 + 255) / 256;

    // ---- build (once per launch) ----
    hipMemsetAsync(bcnt, 0, NBMAX * sizeof(int), stream);
    bucket_hist<<<cb, 256, 0, stream>>>(dst, bcnt, ne);
    bucket_scan<<<1, 1024, 0, stream>>>(bcnt, bbase, cursors, noff, nbuck, n, ne);
    bin_kernel<<<cb, 256, 0, stream>>>(src, dst, cursors, binned0, ne);
    node_sort<<<nbuck, 256, 0, stream>>>(binned0, bbase, binned1, noff, n);

    // ---- layers ----
    sage_dense<32, false><<<nb, 256, 0, stream>>>(x, Wl0, bl0, Wr0, hlb, acc0, n);
    sage_agg<<<ab, 256, 0, stream>>>(noff, binned1, hlb, acc0, n);

    sage_dense<16, true><<<nb, 256, 0, stream>>>(acc0, Wls + 0,   bls + 0,  Wrs + 0,   hlb, acc1, n);
    sage_agg<<<ab, 256, 0, stream>>>(noff, binned1, hlb, acc1, n);

    sage_dense<16, true><<<nb, 256, 0, stream>>>(acc1, Wls + 256, bls + 16, Wrs + 256, hlb, acc0, n);
    sage_agg<<<ab, 256, 0, stream>>>(noff, binned1, hlb, acc0, n);

    sage_dense<16, true><<<nb, 256, 0, stream>>>(acc0, Wls + 512, bls + 32, Wrs + 512, hlb, acc1, n);
    sage_agg<<<ab, 256, 0, stream>>>(noff, binned1, hlb, acc1, n);

    final_mlp<<<nb, 256, 0, stream>>>(acc1, W1, b1, W2, b2, W3, b3, (float*)d_out, n);
}

// Round 5
// 202.778 us; speedup vs baseline: 3.9942x; 1.1525x over previous
//
#include <hip/hip_runtime.h>

// GraphSAGE 4×SAGEConv + MLP head, fp32 in/out.
// R5 vs R4: (a) fast silu via v_rcp_f32 instead of precise-div sequence
// (final_mlp was 52us latency-bound on ~10-op div chains at 1 wave/SIMD);
// (b) sage_agg degree loop unrolled x4 for memory-level parallelism;
// (c) 128-thread blocks for node-parallel kernels (evener CU distribution).

#define SH     7
#define BWID   128            // nodes per bucket (n <= 1<<17 for packing)
#define NBMAX  1024
#define CHUNK  4096
#define EPT    (CHUNK / 256)

__device__ __forceinline__ float silu_f(float v) {
    // v / (1+e^-v) with fast rcp: 1-ulp rel err, tolerance is 2.9e-2
    return v * __builtin_amdgcn_rcpf(1.0f + __expf(-v));
}

__device__ __forceinline__ float bf_lo(unsigned u) { return __uint_as_float(u << 16); }
__device__ __forceinline__ float bf_hi(unsigned u) { return __uint_as_float(u & 0xFFFF0000u); }
__device__ __forceinline__ unsigned short f2bf(float f) {   // RNE
    unsigned x = __float_as_uint(f);
    unsigned r = x + 0x7FFFu + ((x >> 16) & 1u);
    return (unsigned short)(r >> 16);
}
__device__ __forceinline__ unsigned pack_bf2(float a, float b) {
    return (unsigned)f2bf(a) | ((unsigned)f2bf(b) << 16);
}

// ---------------- build ----------------

__global__ __launch_bounds__(256) void bucket_hist(
    const int* __restrict__ dst, int* __restrict__ bcnt, int ne)
{
    __shared__ int sh[NBMAX];
    const int t = threadIdx.x;
    for (int i = t; i < NBMAX; i += 256) sh[i] = 0;
    __syncthreads();
    const int base = blockIdx.x * CHUNK;
    for (int i = t; i < CHUNK; i += 256) {
        const int e = base + i;
        if (e < ne) atomicAdd(&sh[dst[e] >> SH], 1);
    }
    __syncthreads();
    for (int b = t; b < NBMAX; b += 256) {
        const int c = sh[b];
        if (c) atomicAdd(&bcnt[b], c);
    }
}

__global__ __launch_bounds__(1024) void bucket_scan(
    const int* __restrict__ bcnt, int* __restrict__ bbase,
    int* __restrict__ cursors, int* __restrict__ noff, int nbuck, int n, int ne)
{
    __shared__ int sh[NBMAX];
    const int t = threadIdx.x;
    const int c = (t < nbuck) ? bcnt[t] : 0;
    sh[t] = c;
    __syncthreads();
    int v = c;
    for (int off = 1; off < NBMAX; off <<= 1) {
        const int add = (t >= off) ? sh[t - off] : 0;
        __syncthreads();
        v += add;
        sh[t] = v;
        __syncthreads();
    }
    const int excl = v - c;
    if (t < nbuck) { bbase[t] = excl; cursors[t] = excl; }
    if (t == 0) { bbase[nbuck] = ne; noff[n] = ne; }
}

// sort a CHUNK of edges by bucket in LDS, flush bucket-contiguous runs
__global__ __launch_bounds__(256) void bin_kernel(
    const int* __restrict__ src, const int* __restrict__ dst,
    int* __restrict__ cursors, unsigned* __restrict__ binned0, int ne)
{
    __shared__ int   s_hist[NBMAX];
    __shared__ int   s_scan[NBMAX];
    __shared__ int   s_gbase[NBMAX];
    __shared__ int   s_p[256];
    __shared__ uint2 s_items[CHUNK];

    const int t = threadIdx.x;
    const int base = blockIdx.x * CHUNK;
    const int cnt = min(CHUNK, ne - base);

    int es[EPT], ed[EPT];
#pragma unroll
    for (int j = 0; j < EPT; ++j) {
        const int i = t + j * 256;
        if (i < cnt) { es[j] = src[base + i]; ed[j] = dst[base + i]; }
        else         { es[j] = -1; ed[j] = -1; }
    }

    for (int i = t; i < NBMAX; i += 256) s_hist[i] = 0;
    __syncthreads();
#pragma unroll
    for (int j = 0; j < EPT; ++j)
        if (es[j] >= 0) atomicAdd(&s_hist[ed[j] >> SH], 1);
    __syncthreads();

    const int l0 = s_hist[4 * t], l1 = s_hist[4 * t + 1];
    const int l2 = s_hist[4 * t + 2], l3 = s_hist[4 * t + 3];
    const int psum = l0 + l1 + l2 + l3;
    s_p[t] = psum;
    __syncthreads();
    int v = psum;
    for (int off = 1; off < 256; off <<= 1) {
        const int add = (t >= off) ? s_p[t - off] : 0;
        __syncthreads();
        v += add;
        s_p[t] = v;
        __syncthreads();
    }
    const int ex = v - psum;
    s_scan[4 * t] = ex;
    s_scan[4 * t + 1] = ex + l0;
    s_scan[4 * t + 2] = ex + l0 + l1;
    s_scan[4 * t + 3] = ex + l0 + l1 + l2;
    __syncthreads();

    for (int b = t; b < NBMAX; b += 256) {
        const int c = s_hist[b];
        s_gbase[b] = c ? atomicAdd(&cursors[b], c) : 0;
    }
    __syncthreads();
    for (int i = t; i < NBMAX; i += 256) s_hist[i] = 0;
    __syncthreads();

#pragma unroll
    for (int j = 0; j < EPT; ++j) {
        if (es[j] >= 0) {
            const int b  = ed[j] >> SH;
            const int ld = ed[j] & (BWID - 1);
            const int r  = atomicAdd(&s_hist[b], 1);
            s_items[s_scan[b] + r] = make_uint2((unsigned)b,
                                                ((unsigned)ld << 17) | (unsigned)es[j]);
        }
    }
    __syncthreads();

    for (int i = t; i < cnt; i += 256) {
        const uint2 it = s_items[i];
        const int b = (int)it.x;
        binned0[s_gbase[b] + (i - s_scan[b])] = it.y;
    }
}

// per-bucket LDS counting sort by local dst -> per-node-sorted src list + CSR
__global__ __launch_bounds__(256) void node_sort(
    const unsigned* __restrict__ binned0, const int* __restrict__ bbase,
    int* __restrict__ binned1, int* __restrict__ noff, int n)
{
    __shared__ int cnt[BWID];
    __shared__ int off_[BWID];
    const int b = blockIdx.x, t = threadIdx.x;
    const int beg = bbase[b], end = bbase[b + 1];

    if (t < BWID) cnt[t] = 0;
    __syncthreads();
    for (int k = beg + t; k < end; k += 256)
        atomicAdd(&cnt[binned0[k] >> 17], 1);
    __syncthreads();

    if (t < BWID) off_[t] = cnt[t];
    __syncthreads();
    for (int o = 1; o < BWID; o <<= 1) {
        const int add = (t < BWID && t >= o) ? off_[t - o] : 0;
        __syncthreads();
        if (t < BWID) off_[t] += add;
        __syncthreads();
    }
    if (t < BWID) off_[t] -= cnt[t];   // inclusive -> exclusive
    __syncthreads();

    if (t < BWID) {
        const int node = (b << SH) + t;
        if (node <= n) noff[node] = beg + off_[t];
        cnt[t] = 0;                    // reuse as cursor
    }
    __syncthreads();

    for (int k = beg + t; k < end; k += 256) {
        const unsigned u = binned0[k];
        const int ld = (int)(u >> 17);
        const int r = atomicAdd(&cnt[ld], 1);
        binned1[beg + off_[ld] + r] = (int)(u & 0x1FFFFu);
    }
}

// ---------------- layers ----------------

// atomic-free gather: 2 lanes/node, unrolled x4 for memory-level parallelism
__global__ __launch_bounds__(128) void sage_agg(
    const int* __restrict__ noff, const int* __restrict__ binned1,
    const unsigned* __restrict__ hlb, float* __restrict__ acc, int n)
{
    const int tid = blockIdx.x * 128 + threadIdx.x;
    const int node = tid >> 1;
    if (node >= n) return;
    const int q = tid & 1;
    const int beg = noff[node], end = noff[node + 1];

    const uint4* __restrict__ h4 = (const uint4*)hlb;  // [n*2]
    float s[8] = {0.f, 0.f, 0.f, 0.f, 0.f, 0.f, 0.f, 0.f};

    int k = beg;
    for (; k + 4 <= end; k += 4) {
        const int s0 = binned1[k], s1 = binned1[k + 1];
        const int s2 = binned1[k + 2], s3 = binned1[k + 3];
        const uint4 m0 = h4[(size_t)s0 * 2 + q];
        const uint4 m1 = h4[(size_t)s1 * 2 + q];
        const uint4 m2 = h4[(size_t)s2 * 2 + q];
        const uint4 m3 = h4[(size_t)s3 * 2 + q];
        s[0] += bf_lo(m0.x); s[1] += bf_hi(m0.x); s[2] += bf_lo(m0.y); s[3] += bf_hi(m0.y);
        s[4] += bf_lo(m0.z); s[5] += bf_hi(m0.z); s[6] += bf_lo(m0.w); s[7] += bf_hi(m0.w);
        s[0] += bf_lo(m1.x); s[1] += bf_hi(m1.x); s[2] += bf_lo(m1.y); s[3] += bf_hi(m1.y);
        s[4] += bf_lo(m1.z); s[5] += bf_hi(m1.z); s[6] += bf_lo(m1.w); s[7] += bf_hi(m1.w);
        s[0] += bf_lo(m2.x); s[1] += bf_hi(m2.x); s[2] += bf_lo(m2.y); s[3] += bf_hi(m2.y);
        s[4] += bf_lo(m2.z); s[5] += bf_hi(m2.z); s[6] += bf_lo(m2.w); s[7] += bf_hi(m2.w);
        s[0] += bf_lo(m3.x); s[1] += bf_hi(m3.x); s[2] += bf_lo(m3.y); s[3] += bf_hi(m3.y);
        s[4] += bf_lo(m3.z); s[5] += bf_hi(m3.z); s[6] += bf_lo(m3.w); s[7] += bf_hi(m3.w);
    }
    for (; k < end; ++k) {
        const uint4 m = h4[(size_t)binned1[k] * 2 + q];
        s[0] += bf_lo(m.x); s[1] += bf_hi(m.x); s[2] += bf_lo(m.y); s[3] += bf_hi(m.y);
        s[4] += bf_lo(m.z); s[5] += bf_hi(m.z); s[6] += bf_lo(m.w); s[7] += bf_hi(m.w);
    }

    float4* __restrict__ a4 = (float4*)acc;
    float4 a = a4[(size_t)node * 4 + 2 * q];
    a.x += s[0]; a.y += s[1]; a.z += s[2]; a.w += s[3];
    a4[(size_t)node * 4 + 2 * q] = a;
    float4 c = a4[(size_t)node * 4 + 2 * q + 1];
    c.x += s[4]; c.y += s[5]; c.z += s[6]; c.w += s[7];
    a4[(size_t)node * 4 + 2 * q + 1] = c;
}

template <int DIN_, bool SILU_IN>
__global__ __launch_bounds__(128) void sage_dense(
    const float* __restrict__ hin,
    const float* __restrict__ Wl, const float* __restrict__ bl,
    const float* __restrict__ Wr,
    unsigned* __restrict__ hlb,      // out: bf16(Wl * act(hin)) packed [n*8]
    float* __restrict__ acc,         // out: [n,16] = bl + Wr * act(hin)
    int n)
{
    __shared__ float sWl[16 * DIN_];
    __shared__ float sWr[16 * DIN_];
    __shared__ float sbl[16];

    const int t = threadIdx.x;
    for (int i = t; i < 16 * DIN_; i += 128) { sWl[i] = Wl[i]; sWr[i] = Wr[i]; }
    if (t < 16) sbl[t] = bl[t];
    __syncthreads();

    const int node = blockIdx.x * 128 + t;
    if (node >= n) return;

    float h[DIN_];
    const float4* __restrict__ xp = (const float4*)(hin + (size_t)node * DIN_);
#pragma unroll
    for (int q = 0; q < DIN_ / 4; ++q) {
        const float4 v = xp[q];
        h[q * 4 + 0] = v.x; h[q * 4 + 1] = v.y;
        h[q * 4 + 2] = v.z; h[q * 4 + 3] = v.w;
    }
    if (SILU_IN) {
#pragma unroll
        for (int d = 0; d < DIN_; ++d) h[d] = silu_f(h[d]);
    }

    float ol[16], oa[16];
#pragma unroll
    for (int j = 0; j < 16; ++j) {
        float al = 0.0f, ar = 0.0f;
#pragma unroll
        for (int d = 0; d < DIN_; ++d) {
            al = fmaf(sWl[j * DIN_ + d], h[d], al);
            ar = fmaf(sWr[j * DIN_ + d], h[d], ar);
        }
        ol[j] = al;
        oa[j] = sbl[j] + ar;
    }

    unsigned u[8];
#pragma unroll
    for (int q = 0; q < 8; ++q) u[q] = pack_bf2(ol[2 * q], ol[2 * q + 1]);
    uint4* __restrict__ hp = (uint4*)(hlb + (size_t)node * 8);
    hp[0] = make_uint4(u[0], u[1], u[2], u[3]);
    hp[1] = make_uint4(u[4], u[5], u[6], u[7]);

    float4* __restrict__ ap = (float4*)(acc + (size_t)node * 16);
#pragma unroll
    for (int q = 0; q < 4; ++q)
        ap[q] = make_float4(oa[q * 4], oa[q * 4 + 1], oa[q * 4 + 2], oa[q * 4 + 3]);
}

__global__ __launch_bounds__(128) void final_mlp(
    const float* __restrict__ accin,
    const float* __restrict__ W1, const float* __restrict__ b1,
    const float* __restrict__ W2, const float* __restrict__ b2,
    const float* __restrict__ W3, const float* __restrict__ b3,
    float* __restrict__ out, int n)
{
    __shared__ float sW1[32 * 16];
    __shared__ float sW2[32 * 32];
    __shared__ float sb1[32], sb2[32], sW3[32];
    __shared__ float sb3;

    const int t = threadIdx.x;
    for (int i = t; i < 32 * 16; i += 128) sW1[i] = W1[i];
    for (int i = t; i < 32 * 32; i += 128) sW2[i] = W2[i];
    if (t < 32) { sb1[t] = b1[t]; sb2[t] = b2[t]; sW3[t] = W3[t]; }
    if (t == 0) sb3 = b3[0];
    __syncthreads();

    const int node = blockIdx.x * 128 + t;
    if (node >= n) return;

    float h[16];
    const float4* __restrict__ xp = (const float4*)(accin + (size_t)node * 16);
#pragma unroll
    for (int q = 0; q < 4; ++q) {
        const float4 v = xp[q];
        h[q * 4 + 0] = silu_f(v.x); h[q * 4 + 1] = silu_f(v.y);
        h[q * 4 + 2] = silu_f(v.z); h[q * 4 + 3] = silu_f(v.w);
    }

    float a1[32];
#pragma unroll
    for (int j = 0; j < 32; ++j) {
        float s = sb1[j];
#pragma unroll
        for (int d = 0; d < 16; ++d) s = fmaf(sW1[j * 16 + d], h[d], s);
        a1[j] = silu_f(s);
    }

    float o = sb3;
#pragma unroll
    for (int j = 0; j < 32; ++j) {
        float s = sb2[j];
#pragma unroll
        for (int d = 0; d < 32; ++d) s = fmaf(sW2[j * 32 + d], a1[d], s);
        o = fmaf(sW3[j], silu_f(s), o);
    }
    out[node] = o;
}

extern "C" void kernel_launch(void* const* d_in, const int* in_sizes, int n_in,
                              void* d_out, int out_size, void* d_ws, size_t ws_size,
                              hipStream_t stream)
{
    const float* x   = (const float*)d_in[0];
    const int*   ei  = (const int*)d_in[1];
    const float* Wl0 = (const float*)d_in[2];
    const float* bl0 = (const float*)d_in[3];
    const float* Wr0 = (const float*)d_in[4];
    const float* Wls = (const float*)d_in[5];
    const float* bls = (const float*)d_in[6];
    const float* Wrs = (const float*)d_in[7];
    const float* W1  = (const float*)d_in[8];
    const float* b1  = (const float*)d_in[9];
    const float* W2  = (const float*)d_in[10];
    const float* b2  = (const float*)d_in[11];
    const float* W3  = (const float*)d_in[12];
    const float* b3  = (const float*)d_in[13];

    const int n  = in_sizes[0] / 32;
    const int ne = in_sizes[1] / 2;
    const int* src = ei;
    const int* dst = ei + ne;
    const int nbuck = (n + BWID - 1) >> SH;

    // workspace carve-up (~26 MB); hlb aliases binned0 (dead after node_sort)
    float*    acc0    = (float*)d_ws;                        // [n*16]
    float*    acc1    = acc0 + (size_t)n * 16;               // [n*16]
    int*      binned1 = (int*)(acc1 + (size_t)n * 16);       // [ne]
    int*      noff    = binned1 + (size_t)ne;                // [n+1]
    int*      bcnt    = noff + (n + 1);                      // [NBMAX]
    int*      bbase   = bcnt + NBMAX;                        // [NBMAX+1]
    int*      cursors = bbase + NBMAX + 1;                   // [NBMAX]
    unsigned* binned0 = (unsigned*)(cursors + NBMAX);        // [ne]
    unsigned* hlb     = binned0;                             // [n*8] alias

    const int nb  = (n + 127) / 128;
    const int cb  = (ne + CHUNK - 1) / CHUNK;
    const int ab  = (n * 2 + 127) / 128;

    // ---- build (once per launch) ----
    hipMemsetAsync(bcnt, 0, NBMAX * sizeof(int), stream);
    bucket_hist<<<cb, 256, 0, stream>>>(dst, bcnt, ne);
    bucket_scan<<<1, 1024, 0, stream>>>(bcnt, bbase, cursors, noff, nbuck, n, ne);
    bin_kernel<<<cb, 256, 0, stream>>>(src, dst, cursors, binned0, ne);
    node_sort<<<nbuck, 256, 0, stream>>>(binned0, bbase, binned1, noff, n);

    // ---- layers ----
    sage_dense<32, false><<<nb, 128, 0, stream>>>(x, Wl0, bl0, Wr0, hlb, acc0, n);
    sage_agg<<<ab, 128, 0, stream>>>(noff, binned1, hlb, acc0, n);

    sage_dense<16, true><<<nb, 128, 0, stream>>>(acc0, Wls + 0,   bls + 0,  Wrs + 0,   hlb, acc1, n);
    sage_agg<<<ab, 128, 0, stream>>>(noff, binned1, hlb, acc1, n);

    sage_dense<16, true><<<nb, 128, 0, stream>>>(acc1, Wls + 256, bls + 16, Wrs + 256, hlb, acc0, n);
    sage_agg<<<ab, 128, 0, stream>>>(noff, binned1, hlb, acc0, n);

    sage_dense<16, true><<<nb, 128, 0, stream>>>(acc0, Wls + 512, bls + 32, Wrs + 512, hlb, acc1, n);
    sage_agg<<<ab, 128, 0, stream>>>(noff, binned1, hlb, acc1, n);

    final_mlp<<<nb, 128, 0, stream>>>(acc1, W1, b1, W2, b2, W3, b3, (float*)d_out, n);
}

// Round 6
// 189.588 us; speedup vs baseline: 4.2721x; 1.0696x over previous
//
#include <hip/hip_runtime.h>

// GraphSAGE 4×SAGEConv + MLP head, fp32 in/out.
// R6: fuse agg(i)+dense(i+1) (and agg3+MLP) into one kernel per layer:
//   15 -> 10 dispatches, no acc write->read round-trip between agg and dense.
// Gather is 2 lanes/node split by DEGREE (each lane ~deg/2 full 16-wide rows,
// 2x unrolled -> 4 outstanding 16B loads), pair-combined with 16 shfl_xor.
// Both lanes then hold the full h in registers -> dense phase needs no LDS
// exchange (weights in LDS, broadcast reads).

#define SH     7
#define BWID   128            // nodes per bucket (n <= 1<<17 for packing)
#define NBMAX  1024
#define CHUNK  4096
#define EPT    (CHUNK / 256)

__device__ __forceinline__ float silu_f(float v) {
    return v * __builtin_amdgcn_rcpf(1.0f + __expf(-v));
}

__device__ __forceinline__ float bf_lo(unsigned u) { return __uint_as_float(u << 16); }
__device__ __forceinline__ float bf_hi(unsigned u) { return __uint_as_float(u & 0xFFFF0000u); }
__device__ __forceinline__ unsigned short f2bf(float f) {   // RNE
    unsigned x = __float_as_uint(f);
    unsigned r = x + 0x7FFFu + ((x >> 16) & 1u);
    return (unsigned short)(r >> 16);
}
__device__ __forceinline__ unsigned pack_bf2(float a, float b) {
    return (unsigned)f2bf(a) | ((unsigned)f2bf(b) << 16);
}

// ---------------- build ----------------

__global__ __launch_bounds__(256) void bucket_hist(
    const int* __restrict__ dst, int* __restrict__ bcnt, int ne)
{
    __shared__ int sh[NBMAX];
    const int t = threadIdx.x;
    for (int i = t; i < NBMAX; i += 256) sh[i] = 0;
    __syncthreads();
    const int base = blockIdx.x * CHUNK;
    for (int i = t; i < CHUNK; i += 256) {
        const int e = base + i;
        if (e < ne) atomicAdd(&sh[dst[e] >> SH], 1);
    }
    __syncthreads();
    for (int b = t; b < NBMAX; b += 256) {
        const int c = sh[b];
        if (c) atomicAdd(&bcnt[b], c);
    }
}

__global__ __launch_bounds__(1024) void bucket_scan(
    const int* __restrict__ bcnt, int* __restrict__ bbase,
    int* __restrict__ cursors, int* __restrict__ noff, int nbuck, int n, int ne)
{
    __shared__ int sh[NBMAX];
    const int t = threadIdx.x;
    const int c = (t < nbuck) ? bcnt[t] : 0;
    sh[t] = c;
    __syncthreads();
    int v = c;
    for (int off = 1; off < NBMAX; off <<= 1) {
        const int add = (t >= off) ? sh[t - off] : 0;
        __syncthreads();
        v += add;
        sh[t] = v;
        __syncthreads();
    }
    const int excl = v - c;
    if (t < nbuck) { bbase[t] = excl; cursors[t] = excl; }
    if (t == 0) { bbase[nbuck] = ne; noff[n] = ne; }
}

// sort a CHUNK of edges by bucket in LDS, flush bucket-contiguous runs
__global__ __launch_bounds__(256) void bin_kernel(
    const int* __restrict__ src, const int* __restrict__ dst,
    int* __restrict__ cursors, unsigned* __restrict__ binned0, int ne)
{
    __shared__ int   s_hist[NBMAX];
    __shared__ int   s_scan[NBMAX];
    __shared__ int   s_gbase[NBMAX];
    __shared__ int   s_p[256];
    __shared__ uint2 s_items[CHUNK];

    const int t = threadIdx.x;
    const int base = blockIdx.x * CHUNK;
    const int cnt = min(CHUNK, ne - base);

    int es[EPT], ed[EPT];
#pragma unroll
    for (int j = 0; j < EPT; ++j) {
        const int i = t + j * 256;
        if (i < cnt) { es[j] = src[base + i]; ed[j] = dst[base + i]; }
        else         { es[j] = -1; ed[j] = -1; }
    }

    for (int i = t; i < NBMAX; i += 256) s_hist[i] = 0;
    __syncthreads();
#pragma unroll
    for (int j = 0; j < EPT; ++j)
        if (es[j] >= 0) atomicAdd(&s_hist[ed[j] >> SH], 1);
    __syncthreads();

    const int l0 = s_hist[4 * t], l1 = s_hist[4 * t + 1];
    const int l2 = s_hist[4 * t + 2], l3 = s_hist[4 * t + 3];
    const int psum = l0 + l1 + l2 + l3;
    s_p[t] = psum;
    __syncthreads();
    int v = psum;
    for (int off = 1; off < 256; off <<= 1) {
        const int add = (t >= off) ? s_p[t - off] : 0;
        __syncthreads();
        v += add;
        s_p[t] = v;
        __syncthreads();
    }
    const int ex = v - psum;
    s_scan[4 * t] = ex;
    s_scan[4 * t + 1] = ex + l0;
    s_scan[4 * t + 2] = ex + l0 + l1;
    s_scan[4 * t + 3] = ex + l0 + l1 + l2;
    __syncthreads();

    for (int b = t; b < NBMAX; b += 256) {
        const int c = s_hist[b];
        s_gbase[b] = c ? atomicAdd(&cursors[b], c) : 0;
    }
    __syncthreads();
    for (int i = t; i < NBMAX; i += 256) s_hist[i] = 0;
    __syncthreads();

#pragma unroll
    for (int j = 0; j < EPT; ++j) {
        if (es[j] >= 0) {
            const int b  = ed[j] >> SH;
            const int ld = ed[j] & (BWID - 1);
            const int r  = atomicAdd(&s_hist[b], 1);
            s_items[s_scan[b] + r] = make_uint2((unsigned)b,
                                                ((unsigned)ld << 17) | (unsigned)es[j]);
        }
    }
    __syncthreads();

    for (int i = t; i < cnt; i += 256) {
        const uint2 it = s_items[i];
        const int b = (int)it.x;
        binned0[s_gbase[b] + (i - s_scan[b])] = it.y;
    }
}

// per-bucket LDS counting sort by local dst -> per-node-sorted src list + CSR
__global__ __launch_bounds__(256) void node_sort(
    const unsigned* __restrict__ binned0, const int* __restrict__ bbase,
    int* __restrict__ binned1, int* __restrict__ noff, int n)
{
    __shared__ int cnt[BWID];
    __shared__ int off_[BWID];
    const int b = blockIdx.x, t = threadIdx.x;
    const int beg = bbase[b], end = bbase[b + 1];

    if (t < BWID) cnt[t] = 0;
    __syncthreads();
    for (int k = beg + t; k < end; k += 256)
        atomicAdd(&cnt[binned0[k] >> 17], 1);
    __syncthreads();

    if (t < BWID) off_[t] = cnt[t];
    __syncthreads();
    for (int o = 1; o < BWID; o <<= 1) {
        const int add = (t < BWID && t >= o) ? off_[t - o] : 0;
        __syncthreads();
        if (t < BWID) off_[t] += add;
        __syncthreads();
    }
    if (t < BWID) off_[t] -= cnt[t];   // inclusive -> exclusive
    __syncthreads();

    if (t < BWID) {
        const int node = (b << SH) + t;
        if (node <= n) noff[node] = beg + off_[t];
        cnt[t] = 0;                    // reuse as cursor
    }
    __syncthreads();

    for (int k = beg + t; k < end; k += 256) {
        const unsigned u = binned0[k];
        const int ld = (int)(u >> 17);
        const int r = atomicAdd(&cnt[ld], 1);
        binned1[beg + off_[ld] + r] = (int)(u & 0x1FFFFu);
    }
}

// ---------------- layers ----------------

// degree-split gather into p[16]; both lanes end with the FULL combined sum
__device__ __forceinline__ void gather16(
    const int* __restrict__ binned1, const uint4* __restrict__ h4,
    int beg, int end, int q, float* p)
{
#pragma unroll
    for (int i = 0; i < 16; ++i) p[i] = 0.f;
    int k = beg + q;
    for (; k + 2 < end; k += 4) {       // two edges per iter for this lane
        const int s0 = binned1[k];
        const int s1 = binned1[k + 2];
        const uint4 a0 = h4[(size_t)s0 * 2];
        const uint4 a1 = h4[(size_t)s0 * 2 + 1];
        const uint4 b0 = h4[(size_t)s1 * 2];
        const uint4 b1 = h4[(size_t)s1 * 2 + 1];
        p[0] += bf_lo(a0.x); p[1] += bf_hi(a0.x); p[2] += bf_lo(a0.y); p[3] += bf_hi(a0.y);
        p[4] += bf_lo(a0.z); p[5] += bf_hi(a0.z); p[6] += bf_lo(a0.w); p[7] += bf_hi(a0.w);
        p[8] += bf_lo(a1.x); p[9] += bf_hi(a1.x); p[10]+= bf_lo(a1.y); p[11]+= bf_hi(a1.y);
        p[12]+= bf_lo(a1.z); p[13]+= bf_hi(a1.z); p[14]+= bf_lo(a1.w); p[15]+= bf_hi(a1.w);
        p[0] += bf_lo(b0.x); p[1] += bf_hi(b0.x); p[2] += bf_lo(b0.y); p[3] += bf_hi(b0.y);
        p[4] += bf_lo(b0.z); p[5] += bf_hi(b0.z); p[6] += bf_lo(b0.w); p[7] += bf_hi(b0.w);
        p[8] += bf_lo(b1.x); p[9] += bf_hi(b1.x); p[10]+= bf_lo(b1.y); p[11]+= bf_hi(b1.y);
        p[12]+= bf_lo(b1.z); p[13]+= bf_hi(b1.z); p[14]+= bf_lo(b1.w); p[15]+= bf_hi(b1.w);
    }
    if (k < end) {
        const int s0 = binned1[k];
        const uint4 a0 = h4[(size_t)s0 * 2];
        const uint4 a1 = h4[(size_t)s0 * 2 + 1];
        p[0] += bf_lo(a0.x); p[1] += bf_hi(a0.x); p[2] += bf_lo(a0.y); p[3] += bf_hi(a0.y);
        p[4] += bf_lo(a0.z); p[5] += bf_hi(a0.z); p[6] += bf_lo(a0.w); p[7] += bf_hi(a0.w);
        p[8] += bf_lo(a1.x); p[9] += bf_hi(a1.x); p[10]+= bf_lo(a1.y); p[11]+= bf_hi(a1.y);
        p[12]+= bf_lo(a1.z); p[13]+= bf_hi(a1.z); p[14]+= bf_lo(a1.w); p[15]+= bf_hi(a1.w);
    }
#pragma unroll
    for (int i = 0; i < 16; ++i) p[i] += __shfl_xor(p[i], 1);   // pair combine
}

// agg(layer i) + dense(layer i+1): 256 thr = 128 nodes x 2 lanes, block=bucket
__global__ __launch_bounds__(256) void fused_agg_dense(
    const int* __restrict__ noff, const int* __restrict__ binned1,
    const unsigned* __restrict__ hl_in,   // [n*8] bf16x2 (layer i messages)
    const float* __restrict__ acc_in,     // [n*16] accinit_i
    const float* __restrict__ Wl, const float* __restrict__ bl,
    const float* __restrict__ Wr,
    unsigned* __restrict__ hl_out,        // [n*8] layer i+1 messages
    float* __restrict__ acc_out,          // [n*16] accinit_{i+1}
    int n)
{
    __shared__ float sWl[256], sWr[256], sbl[16];
    const int t = threadIdx.x;
    if (t < 256) { sWl[t] = Wl[t]; sWr[t] = Wr[t]; }
    if (t < 16) sbl[t] = bl[t];
    __syncthreads();

    const int node = (blockIdx.x << SH) + (t >> 1);
    if (node >= n) return;
    const int q = t & 1;
    const int beg = noff[node], end = noff[node + 1];

    float p[16];
    gather16(binned1, (const uint4*)hl_in, beg, end, q, p);

    // h = silu(accinit + gathered)  (full 16 in both lanes)
    const float4* __restrict__ ai = (const float4*)(acc_in + (size_t)node * 16);
    float h[16];
#pragma unroll
    for (int r = 0; r < 4; ++r) {
        const float4 a = ai[r];
        h[4*r+0] = silu_f(a.x + p[4*r+0]);
        h[4*r+1] = silu_f(a.y + p[4*r+1]);
        h[4*r+2] = silu_f(a.z + p[4*r+2]);
        h[4*r+3] = silu_f(a.w + p[4*r+3]);
    }

    // dense: lane q computes outputs j in [8q, 8q+8)
    float ol[8], oa[8];
#pragma unroll
    for (int jj = 0; jj < 8; ++jj) {
        const int j = 8 * q + jj;
        float al = 0.f, ar = 0.f;
#pragma unroll
        for (int d = 0; d < 16; ++d) {
            al = fmaf(sWl[j * 16 + d], h[d], al);
            ar = fmaf(sWr[j * 16 + d], h[d], ar);
        }
        ol[jj] = al;
        oa[jj] = sbl[j] + ar;
    }

    ((uint4*)hl_out)[(size_t)node * 2 + q] =
        make_uint4(pack_bf2(ol[0], ol[1]), pack_bf2(ol[2], ol[3]),
                   pack_bf2(ol[4], ol[5]), pack_bf2(ol[6], ol[7]));
    float4* __restrict__ ap = (float4*)(acc_out + (size_t)node * 16);
    ap[2 * q]     = make_float4(oa[0], oa[1], oa[2], oa[3]);
    ap[2 * q + 1] = make_float4(oa[4], oa[5], oa[6], oa[7]);
}

// agg(layer 3) + MLP head
__global__ __launch_bounds__(256) void fused_agg_mlp(
    const int* __restrict__ noff, const int* __restrict__ binned1,
    const unsigned* __restrict__ hl_in, const float* __restrict__ acc_in,
    const float* __restrict__ W1, const float* __restrict__ b1,
    const float* __restrict__ W2, const float* __restrict__ b2,
    const float* __restrict__ W3, const float* __restrict__ b3,
    float* __restrict__ out, int n)
{
    __shared__ float sW1[512], sW2[1024], sb1[32], sb2[32], sW3[32];
    __shared__ float sb3;
    const int t = threadIdx.x;
    for (int i = t; i < 512; i += 256) sW1[i] = W1[i];
    for (int i = t; i < 1024; i += 256) sW2[i] = W2[i];
    if (t < 32) { sb1[t] = b1[t]; sb2[t] = b2[t]; sW3[t] = W3[t]; }
    if (t == 0) sb3 = b3[0];
    __syncthreads();

    const int node = (blockIdx.x << SH) + (t >> 1);
    if (node >= n) return;
    const int q = t & 1;
    const int beg = noff[node], end = noff[node + 1];

    float p[16];
    gather16(binned1, (const uint4*)hl_in, beg, end, q, p);

    const float4* __restrict__ ai = (const float4*)(acc_in + (size_t)node * 16);
    float h[16];
#pragma unroll
    for (int r = 0; r < 4; ++r) {
        const float4 a = ai[r];
        h[4*r+0] = silu_f(a.x + p[4*r+0]);
        h[4*r+1] = silu_f(a.y + p[4*r+1]);
        h[4*r+2] = silu_f(a.z + p[4*r+2]);
        h[4*r+3] = silu_f(a.w + p[4*r+3]);
    }

    // layer1: lane q computes a1[j], j in [16q, 16q+16)
    float a1[16];
#pragma unroll
    for (int jj = 0; jj < 16; ++jj) {
        const int j = 16 * q + jj;
        float s = sb1[j];
#pragma unroll
        for (int d = 0; d < 16; ++d) s = fmaf(sW1[j * 16 + d], h[d], s);
        a1[jj] = silu_f(s);
    }

    // exchange: both lanes assemble full A1[32]
    float A1[32];
#pragma unroll
    for (int i = 0; i < 16; ++i) {
        const float o = __shfl_xor(a1[i], 1);
        A1[16 * q + i] = a1[i];
        A1[16 * (1 - q) + i] = o;
    }

    // layer2 + output partial
    float part = 0.f;
#pragma unroll
    for (int jj = 0; jj < 16; ++jj) {
        const int j = 16 * q + jj;
        float s = sb2[j];
#pragma unroll
        for (int d = 0; d < 32; ++d) s = fmaf(sW2[j * 32 + d], A1[d], s);
        part = fmaf(sW3[j], silu_f(s), part);
    }
    part += __shfl_xor(part, 1);
    if (q == 0) out[node] = part + sb3;
}

// layer 0 dense (from raw x, no input activation)
__global__ __launch_bounds__(128) void dense0(
    const float* __restrict__ x,
    const float* __restrict__ Wl, const float* __restrict__ bl,
    const float* __restrict__ Wr,
    unsigned* __restrict__ hlb, float* __restrict__ acc, int n)
{
    __shared__ float sWl[512], sWr[512], sbl[16];
    const int t = threadIdx.x;
    for (int i = t; i < 512; i += 128) { sWl[i] = Wl[i]; sWr[i] = Wr[i]; }
    if (t < 16) sbl[t] = bl[t];
    __syncthreads();

    const int node = blockIdx.x * 128 + t;
    if (node >= n) return;

    float h[32];
    const float4* __restrict__ xp = (const float4*)(x + (size_t)node * 32);
#pragma unroll
    for (int r = 0; r < 8; ++r) {
        const float4 v = xp[r];
        h[4*r+0] = v.x; h[4*r+1] = v.y; h[4*r+2] = v.z; h[4*r+3] = v.w;
    }

    float ol[16], oa[16];
#pragma unroll
    for (int j = 0; j < 16; ++j) {
        float al = 0.f, ar = 0.f;
#pragma unroll
        for (int d = 0; d < 32; ++d) {
            al = fmaf(sWl[j * 32 + d], h[d], al);
            ar = fmaf(sWr[j * 32 + d], h[d], ar);
        }
        ol[j] = al;
        oa[j] = sbl[j] + ar;
    }

    unsigned u[8];
#pragma unroll
    for (int r = 0; r < 8; ++r) u[r] = pack_bf2(ol[2*r], ol[2*r+1]);
    uint4* __restrict__ hp = (uint4*)(hlb + (size_t)node * 8);
    hp[0] = make_uint4(u[0], u[1], u[2], u[3]);
    hp[1] = make_uint4(u[4], u[5], u[6], u[7]);
    float4* __restrict__ ap = (float4*)(acc + (size_t)node * 16);
#pragma unroll
    for (int r = 0; r < 4; ++r)
        ap[r] = make_float4(oa[4*r], oa[4*r+1], oa[4*r+2], oa[4*r+3]);
}

extern "C" void kernel_launch(void* const* d_in, const int* in_sizes, int n_in,
                              void* d_out, int out_size, void* d_ws, size_t ws_size,
                              hipStream_t stream)
{
    const float* x   = (const float*)d_in[0];
    const int*   ei  = (const int*)d_in[1];
    const float* Wl0 = (const float*)d_in[2];
    const float* bl0 = (const float*)d_in[3];
    const float* Wr0 = (const float*)d_in[4];
    const float* Wls = (const float*)d_in[5];
    const float* bls = (const float*)d_in[6];
    const float* Wrs = (const float*)d_in[7];
    const float* W1  = (const float*)d_in[8];
    const float* b1  = (const float*)d_in[9];
    const float* W2  = (const float*)d_in[10];
    const float* b2  = (const float*)d_in[11];
    const float* W3  = (const float*)d_in[12];
    const float* b3  = (const float*)d_in[13];

    const int n  = in_sizes[0] / 32;
    const int ne = in_sizes[1] / 2;
    const int* src = ei;
    const int* dst = ei + ne;
    const int nbuck = (n + BWID - 1) >> SH;

    // workspace (~33 MB, ws is ~268 MB per harness fill size)
    float*    acc0    = (float*)d_ws;                        // [n*16]
    float*    acc1    = acc0 + (size_t)n * 16;               // [n*16]
    unsigned* hlbA    = (unsigned*)(acc1 + (size_t)n * 16);  // [n*8]
    unsigned* hlbB    = hlbA + (size_t)n * 8;                // [n*8]
    int*      binned1 = (int*)(hlbB + (size_t)n * 8);        // [ne]
    int*      noff    = binned1 + (size_t)ne;                // [n+1]
    int*      bcnt    = noff + (n + 1);                      // [NBMAX]
    int*      bbase   = bcnt + NBMAX;                        // [NBMAX+1]
    int*      cursors = bbase + NBMAX + 1;                   // [NBMAX]
    unsigned* binned0 = (unsigned*)(cursors + NBMAX);        // [ne]

    const int nb = (n + 127) / 128;
    const int cb = (ne + CHUNK - 1) / CHUNK;

    // ---- build ----
    hipMemsetAsync(bcnt, 0, NBMAX * sizeof(int), stream);
    bucket_hist<<<cb, 256, 0, stream>>>(dst, bcnt, ne);
    bucket_scan<<<1, 1024, 0, stream>>>(bcnt, bbase, cursors, noff, nbuck, n, ne);
    bin_kernel<<<cb, 256, 0, stream>>>(src, dst, cursors, binned0, ne);
    node_sort<<<nbuck, 256, 0, stream>>>(binned0, bbase, binned1, noff, n);

    // ---- layers (hl ping-pong A/B; acc ping-pong 0/1) ----
    dense0<<<nb, 128, 0, stream>>>(x, Wl0, bl0, Wr0, hlbA, acc0, n);
    fused_agg_dense<<<nbuck, 256, 0, stream>>>(noff, binned1, hlbA, acc0,
        Wls + 0,   bls + 0,  Wrs + 0,   hlbB, acc1, n);
    fused_agg_dense<<<nbuck, 256, 0, stream>>>(noff, binned1, hlbB, acc1,
        Wls + 256, bls + 16, Wrs + 256, hlbA, acc0, n);
    fused_agg_dense<<<nbuck, 256, 0, stream>>>(noff, binned1, hlbA, acc0,
        Wls + 512, bls + 32, Wrs + 512, hlbB, acc1, n);
    fused_agg_mlp<<<nbuck, 256, 0, stream>>>(noff, binned1, hlbB, acc1,
        W1, b1, W2, b2, W3, b3, (float*)d_out, n);
}

// Round 7
// 177.800 us; speedup vs baseline: 4.5553x; 1.0663x over previous
//
#include <hip/hip_runtime.h>

// GraphSAGE 4×SAGEConv + MLP head, fp32 in/out.
// R7 vs R6: fused_agg_mlp had A1[] indexed by runtime q -> compiler demoted it
// to scratch (VGPR=60, 50-60us latency-bound on scratch loads). Fixed with
// compile-time-indexed cndmask assembly. Also float4 (ds_read_b128) weight
// reads in both fused kernels (4x fewer LDS instructions).

#define SH     7
#define BWID   128            // nodes per bucket (n <= 1<<17 for packing)
#define NBMAX  1024
#define CHUNK  4096
#define EPT    (CHUNK / 256)

__device__ __forceinline__ float silu_f(float v) {
    return v * __builtin_amdgcn_rcpf(1.0f + __expf(-v));
}

__device__ __forceinline__ float bf_lo(unsigned u) { return __uint_as_float(u << 16); }
__device__ __forceinline__ float bf_hi(unsigned u) { return __uint_as_float(u & 0xFFFF0000u); }
__device__ __forceinline__ unsigned short f2bf(float f) {   // RNE
    unsigned x = __float_as_uint(f);
    unsigned r = x + 0x7FFFu + ((x >> 16) & 1u);
    return (unsigned short)(r >> 16);
}
__device__ __forceinline__ unsigned pack_bf2(float a, float b) {
    return (unsigned)f2bf(a) | ((unsigned)f2bf(b) << 16);
}

// ---------------- build ----------------

__global__ __launch_bounds__(256) void bucket_hist(
    const int* __restrict__ dst, int* __restrict__ bcnt, int ne)
{
    __shared__ int sh[NBMAX];
    const int t = threadIdx.x;
    for (int i = t; i < NBMAX; i += 256) sh[i] = 0;
    __syncthreads();
    const int base = blockIdx.x * CHUNK;
    for (int i = t; i < CHUNK; i += 256) {
        const int e = base + i;
        if (e < ne) atomicAdd(&sh[dst[e] >> SH], 1);
    }
    __syncthreads();
    for (int b = t; b < NBMAX; b += 256) {
        const int c = sh[b];
        if (c) atomicAdd(&bcnt[b], c);
    }
}

__global__ __launch_bounds__(1024) void bucket_scan(
    const int* __restrict__ bcnt, int* __restrict__ bbase,
    int* __restrict__ cursors, int* __restrict__ noff, int nbuck, int n, int ne)
{
    __shared__ int sh[NBMAX];
    const int t = threadIdx.x;
    const int c = (t < nbuck) ? bcnt[t] : 0;
    sh[t] = c;
    __syncthreads();
    int v = c;
    for (int off = 1; off < NBMAX; off <<= 1) {
        const int add = (t >= off) ? sh[t - off] : 0;
        __syncthreads();
        v += add;
        sh[t] = v;
        __syncthreads();
    }
    const int excl = v - c;
    if (t < nbuck) { bbase[t] = excl; cursors[t] = excl; }
    if (t == 0) { bbase[nbuck] = ne; noff[n] = ne; }
}

// sort a CHUNK of edges by bucket in LDS, flush bucket-contiguous runs
__global__ __launch_bounds__(256) void bin_kernel(
    const int* __restrict__ src, const int* __restrict__ dst,
    int* __restrict__ cursors, unsigned* __restrict__ binned0, int ne)
{
    __shared__ int   s_hist[NBMAX];
    __shared__ int   s_scan[NBMAX];
    __shared__ int   s_gbase[NBMAX];
    __shared__ int   s_p[256];
    __shared__ uint2 s_items[CHUNK];

    const int t = threadIdx.x;
    const int base = blockIdx.x * CHUNK;
    const int cnt = min(CHUNK, ne - base);

    int es[EPT], ed[EPT];
#pragma unroll
    for (int j = 0; j < EPT; ++j) {
        const int i = t + j * 256;
        if (i < cnt) { es[j] = src[base + i]; ed[j] = dst[base + i]; }
        else         { es[j] = -1; ed[j] = -1; }
    }

    for (int i = t; i < NBMAX; i += 256) s_hist[i] = 0;
    __syncthreads();
#pragma unroll
    for (int j = 0; j < EPT; ++j)
        if (es[j] >= 0) atomicAdd(&s_hist[ed[j] >> SH], 1);
    __syncthreads();

    const int l0 = s_hist[4 * t], l1 = s_hist[4 * t + 1];
    const int l2 = s_hist[4 * t + 2], l3 = s_hist[4 * t + 3];
    const int psum = l0 + l1 + l2 + l3;
    s_p[t] = psum;
    __syncthreads();
    int v = psum;
    for (int off = 1; off < 256; off <<= 1) {
        const int add = (t >= off) ? s_p[t - off] : 0;
        __syncthreads();
        v += add;
        s_p[t] = v;
        __syncthreads();
    }
    const int ex = v - psum;
    s_scan[4 * t] = ex;
    s_scan[4 * t + 1] = ex + l0;
    s_scan[4 * t + 2] = ex + l0 + l1;
    s_scan[4 * t + 3] = ex + l0 + l1 + l2;
    __syncthreads();

    for (int b = t; b < NBMAX; b += 256) {
        const int c = s_hist[b];
        s_gbase[b] = c ? atomicAdd(&cursors[b], c) : 0;
    }
    __syncthreads();
    for (int i = t; i < NBMAX; i += 256) s_hist[i] = 0;
    __syncthreads();

#pragma unroll
    for (int j = 0; j < EPT; ++j) {
        if (es[j] >= 0) {
            const int b  = ed[j] >> SH;
            const int ld = ed[j] & (BWID - 1);
            const int r  = atomicAdd(&s_hist[b], 1);
            s_items[s_scan[b] + r] = make_uint2((unsigned)b,
                                                ((unsigned)ld << 17) | (unsigned)es[j]);
        }
    }
    __syncthreads();

    for (int i = t; i < cnt; i += 256) {
        const uint2 it = s_items[i];
        const int b = (int)it.x;
        binned0[s_gbase[b] + (i - s_scan[b])] = it.y;
    }
}

// per-bucket LDS counting sort by local dst -> per-node-sorted src list + CSR
__global__ __launch_bounds__(256) void node_sort(
    const unsigned* __restrict__ binned0, const int* __restrict__ bbase,
    int* __restrict__ binned1, int* __restrict__ noff, int n)
{
    __shared__ int cnt[BWID];
    __shared__ int off_[BWID];
    const int b = blockIdx.x, t = threadIdx.x;
    const int beg = bbase[b], end = bbase[b + 1];

    if (t < BWID) cnt[t] = 0;
    __syncthreads();
    for (int k = beg + t; k < end; k += 256)
        atomicAdd(&cnt[binned0[k] >> 17], 1);
    __syncthreads();

    if (t < BWID) off_[t] = cnt[t];
    __syncthreads();
    for (int o = 1; o < BWID; o <<= 1) {
        const int add = (t < BWID && t >= o) ? off_[t - o] : 0;
        __syncthreads();
        if (t < BWID) off_[t] += add;
        __syncthreads();
    }
    if (t < BWID) off_[t] -= cnt[t];   // inclusive -> exclusive
    __syncthreads();

    if (t < BWID) {
        const int node = (b << SH) + t;
        if (node <= n) noff[node] = beg + off_[t];
        cnt[t] = 0;                    // reuse as cursor
    }
    __syncthreads();

    for (int k = beg + t; k < end; k += 256) {
        const unsigned u = binned0[k];
        const int ld = (int)(u >> 17);
        const int r = atomicAdd(&cnt[ld], 1);
        binned1[beg + off_[ld] + r] = (int)(u & 0x1FFFFu);
    }
}

// ---------------- layers ----------------

// degree-split gather into p[16]; both lanes end with the FULL combined sum
__device__ __forceinline__ void gather16(
    const int* __restrict__ binned1, const uint4* __restrict__ h4,
    int beg, int end, int q, float* p)
{
#pragma unroll
    for (int i = 0; i < 16; ++i) p[i] = 0.f;
    int k = beg + q;
    for (; k + 2 < end; k += 4) {       // two edges per iter for this lane
        const int s0 = binned1[k];
        const int s1 = binned1[k + 2];
        const uint4 a0 = h4[(size_t)s0 * 2];
        const uint4 a1 = h4[(size_t)s0 * 2 + 1];
        const uint4 b0 = h4[(size_t)s1 * 2];
        const uint4 b1 = h4[(size_t)s1 * 2 + 1];
        p[0] += bf_lo(a0.x); p[1] += bf_hi(a0.x); p[2] += bf_lo(a0.y); p[3] += bf_hi(a0.y);
        p[4] += bf_lo(a0.z); p[5] += bf_hi(a0.z); p[6] += bf_lo(a0.w); p[7] += bf_hi(a0.w);
        p[8] += bf_lo(a1.x); p[9] += bf_hi(a1.x); p[10]+= bf_lo(a1.y); p[11]+= bf_hi(a1.y);
        p[12]+= bf_lo(a1.z); p[13]+= bf_hi(a1.z); p[14]+= bf_lo(a1.w); p[15]+= bf_hi(a1.w);
        p[0] += bf_lo(b0.x); p[1] += bf_hi(b0.x); p[2] += bf_lo(b0.y); p[3] += bf_hi(b0.y);
        p[4] += bf_lo(b0.z); p[5] += bf_hi(b0.z); p[6] += bf_lo(b0.w); p[7] += bf_hi(b0.w);
        p[8] += bf_lo(b1.x); p[9] += bf_hi(b1.x); p[10]+= bf_lo(b1.y); p[11]+= bf_hi(b1.y);
        p[12]+= bf_lo(b1.z); p[13]+= bf_hi(b1.z); p[14]+= bf_lo(b1.w); p[15]+= bf_hi(b1.w);
    }
    if (k < end) {
        const int s0 = binned1[k];
        const uint4 a0 = h4[(size_t)s0 * 2];
        const uint4 a1 = h4[(size_t)s0 * 2 + 1];
        p[0] += bf_lo(a0.x); p[1] += bf_hi(a0.x); p[2] += bf_lo(a0.y); p[3] += bf_hi(a0.y);
        p[4] += bf_lo(a0.z); p[5] += bf_hi(a0.z); p[6] += bf_lo(a0.w); p[7] += bf_hi(a0.w);
        p[8] += bf_lo(a1.x); p[9] += bf_hi(a1.x); p[10]+= bf_lo(a1.y); p[11]+= bf_hi(a1.y);
        p[12]+= bf_lo(a1.z); p[13]+= bf_hi(a1.z); p[14]+= bf_lo(a1.w); p[15]+= bf_hi(a1.w);
    }
#pragma unroll
    for (int i = 0; i < 16; ++i) p[i] += __shfl_xor(p[i], 1);   // pair combine
}

// agg(layer i) + dense(layer i+1): 256 thr = 128 nodes x 2 lanes, block=bucket
__global__ __launch_bounds__(256) void fused_agg_dense(
    const int* __restrict__ noff, const int* __restrict__ binned1,
    const unsigned* __restrict__ hl_in,   // [n*8] bf16x2 (layer i messages)
    const float* __restrict__ acc_in,     // [n*16] accinit_i
    const float* __restrict__ Wl, const float* __restrict__ bl,
    const float* __restrict__ Wr,
    unsigned* __restrict__ hl_out,        // [n*8] layer i+1 messages
    float* __restrict__ acc_out,          // [n*16] accinit_{i+1}
    int n)
{
    __shared__ float sWl[256], sWr[256], sbl[16];
    const int t = threadIdx.x;
    if (t < 256) { sWl[t] = Wl[t]; sWr[t] = Wr[t]; }
    if (t < 16) sbl[t] = bl[t];
    __syncthreads();

    const int node = (blockIdx.x << SH) + (t >> 1);
    if (node >= n) return;
    const int q = t & 1;
    const int beg = noff[node], end = noff[node + 1];

    float p[16];
    gather16(binned1, (const uint4*)hl_in, beg, end, q, p);

    // h = silu(accinit + gathered)  (full 16 in both lanes)
    const float4* __restrict__ ai = (const float4*)(acc_in + (size_t)node * 16);
    float h[16];
#pragma unroll
    for (int r = 0; r < 4; ++r) {
        const float4 a = ai[r];
        h[4*r+0] = silu_f(a.x + p[4*r+0]);
        h[4*r+1] = silu_f(a.y + p[4*r+1]);
        h[4*r+2] = silu_f(a.z + p[4*r+2]);
        h[4*r+3] = silu_f(a.w + p[4*r+3]);
    }

    // dense: lane q computes outputs j in [8q, 8q+8); float4 LDS weight reads
    const float4* __restrict__ sWl4 = (const float4*)sWl;
    const float4* __restrict__ sWr4 = (const float4*)sWr;
    float ol[8], oa[8];
#pragma unroll
    for (int jj = 0; jj < 8; ++jj) {
        const int j = 8 * q + jj;
        float al = 0.f, ar = 0.f;
#pragma unroll
        for (int d4 = 0; d4 < 4; ++d4) {
            const float4 wl = sWl4[j * 4 + d4];
            const float4 wr = sWr4[j * 4 + d4];
            al = fmaf(wl.x, h[4*d4+0], al); al = fmaf(wl.y, h[4*d4+1], al);
            al = fmaf(wl.z, h[4*d4+2], al); al = fmaf(wl.w, h[4*d4+3], al);
            ar = fmaf(wr.x, h[4*d4+0], ar); ar = fmaf(wr.y, h[4*d4+1], ar);
            ar = fmaf(wr.z, h[4*d4+2], ar); ar = fmaf(wr.w, h[4*d4+3], ar);
        }
        ol[jj] = al;
        oa[jj] = sbl[j] + ar;
    }

    ((uint4*)hl_out)[(size_t)node * 2 + q] =
        make_uint4(pack_bf2(ol[0], ol[1]), pack_bf2(ol[2], ol[3]),
                   pack_bf2(ol[4], ol[5]), pack_bf2(ol[6], ol[7]));
    float4* __restrict__ ap = (float4*)(acc_out + (size_t)node * 16);
    ap[2 * q]     = make_float4(oa[0], oa[1], oa[2], oa[3]);
    ap[2 * q + 1] = make_float4(oa[4], oa[5], oa[6], oa[7]);
}

// agg(layer 3) + MLP head
__global__ __launch_bounds__(256) void fused_agg_mlp(
    const int* __restrict__ noff, const int* __restrict__ binned1,
    const unsigned* __restrict__ hl_in, const float* __restrict__ acc_in,
    const float* __restrict__ W1, const float* __restrict__ b1,
    const float* __restrict__ W2, const float* __restrict__ b2,
    const float* __restrict__ W3, const float* __restrict__ b3,
    float* __restrict__ out, int n)
{
    __shared__ float sW1[512], sW2[1024], sb1[32], sb2[32], sW3[32];
    __shared__ float sb3;
    const int t = threadIdx.x;
    for (int i = t; i < 512; i += 256) sW1[i] = W1[i];
    for (int i = t; i < 1024; i += 256) sW2[i] = W2[i];
    if (t < 32) { sb1[t] = b1[t]; sb2[t] = b2[t]; sW3[t] = W3[t]; }
    if (t == 0) sb3 = b3[0];
    __syncthreads();

    const int node = (blockIdx.x << SH) + (t >> 1);
    if (node >= n) return;
    const int q = t & 1;
    const int beg = noff[node], end = noff[node + 1];

    float p[16];
    gather16(binned1, (const uint4*)hl_in, beg, end, q, p);

    const float4* __restrict__ ai = (const float4*)(acc_in + (size_t)node * 16);
    float h[16];
#pragma unroll
    for (int r = 0; r < 4; ++r) {
        const float4 a = ai[r];
        h[4*r+0] = silu_f(a.x + p[4*r+0]);
        h[4*r+1] = silu_f(a.y + p[4*r+1]);
        h[4*r+2] = silu_f(a.z + p[4*r+2]);
        h[4*r+3] = silu_f(a.w + p[4*r+3]);
    }

    // layer1: lane q computes a1[j], j in [16q, 16q+16); float4 weight reads
    const float4* __restrict__ sW1v = (const float4*)sW1;
    float a1[16];
#pragma unroll
    for (int jj = 0; jj < 16; ++jj) {
        const int j = 16 * q + jj;
        float s = sb1[j];
#pragma unroll
        for (int d4 = 0; d4 < 4; ++d4) {
            const float4 w = sW1v[j * 4 + d4];
            s = fmaf(w.x, h[4*d4+0], s); s = fmaf(w.y, h[4*d4+1], s);
            s = fmaf(w.z, h[4*d4+2], s); s = fmaf(w.w, h[4*d4+3], s);
        }
        a1[jj] = silu_f(s);
    }

    // exchange: both lanes assemble full A1[32] with COMPILE-TIME indices
    // (runtime 16*q+i indexing sent A1 to scratch in R6: VGPR=60, 50-60us)
    float A1[32];
#pragma unroll
    for (int i = 0; i < 16; ++i) {
        const float mine  = a1[i];
        const float other = __shfl_xor(mine, 1);
        A1[i]      = q ? other : mine;
        A1[16 + i] = q ? mine  : other;
    }

    // layer2 + output partial; float4 weight reads
    const float4* __restrict__ sW2v = (const float4*)sW2;
    float part = 0.f;
#pragma unroll
    for (int jj = 0; jj < 16; ++jj) {
        const int j = 16 * q + jj;
        float s = sb2[j];
#pragma unroll
        for (int d4 = 0; d4 < 8; ++d4) {
            const float4 w = sW2v[j * 8 + d4];
            s = fmaf(w.x, A1[4*d4+0], s); s = fmaf(w.y, A1[4*d4+1], s);
            s = fmaf(w.z, A1[4*d4+2], s); s = fmaf(w.w, A1[4*d4+3], s);
        }
        part = fmaf(sW3[j], silu_f(s), part);
    }
    part += __shfl_xor(part, 1);
    if (q == 0) out[node] = part + sb3;
}

// layer 0 dense (from raw x, no input activation)
__global__ __launch_bounds__(128) void dense0(
    const float* __restrict__ x,
    const float* __restrict__ Wl, const float* __restrict__ bl,
    const float* __restrict__ Wr,
    unsigned* __restrict__ hlb, float* __restrict__ acc, int n)
{
    __shared__ float sWl[512], sWr[512], sbl[16];
    const int t = threadIdx.x;
    for (int i = t; i < 512; i += 128) { sWl[i] = Wl[i]; sWr[i] = Wr[i]; }
    if (t < 16) sbl[t] = bl[t];
    __syncthreads();

    const int node = blockIdx.x * 128 + t;
    if (node >= n) return;

    float h[32];
    const float4* __restrict__ xp = (const float4*)(x + (size_t)node * 32);
#pragma unroll
    for (int r = 0; r < 8; ++r) {
        const float4 v = xp[r];
        h[4*r+0] = v.x; h[4*r+1] = v.y; h[4*r+2] = v.z; h[4*r+3] = v.w;
    }

    const float4* __restrict__ sWl4 = (const float4*)sWl;
    const float4* __restrict__ sWr4 = (const float4*)sWr;
    float ol[16], oa[16];
#pragma unroll
    for (int j = 0; j < 16; ++j) {
        float al = 0.f, ar = 0.f;
#pragma unroll
        for (int d4 = 0; d4 < 8; ++d4) {
            const float4 wl = sWl4[j * 8 + d4];
            const float4 wr = sWr4[j * 8 + d4];
            al = fmaf(wl.x, h[4*d4+0], al); al = fmaf(wl.y, h[4*d4+1], al);
            al = fmaf(wl.z, h[4*d4+2], al); al = fmaf(wl.w, h[4*d4+3], al);
            ar = fmaf(wr.x, h[4*d4+0], ar); ar = fmaf(wr.y, h[4*d4+1], ar);
            ar = fmaf(wr.z, h[4*d4+2], ar); ar = fmaf(wr.w, h[4*d4+3], ar);
        }
        ol[j] = al;
        oa[j] = sbl[j] + ar;
    }

    unsigned u[8];
#pragma unroll
    for (int r = 0; r < 8; ++r) u[r] = pack_bf2(ol[2*r], ol[2*r+1]);
    uint4* __restrict__ hp = (uint4*)(hlb + (size_t)node * 8);
    hp[0] = make_uint4(u[0], u[1], u[2], u[3]);
    hp[1] = make_uint4(u[4], u[5], u[6], u[7]);
    float4* __restrict__ ap = (float4*)(acc + (size_t)node * 16);
#pragma unroll
    for (int r = 0; r < 4; ++r)
        ap[r] = make_float4(oa[4*r], oa[4*r+1], oa[4*r+2], oa[4*r+3]);
}

extern "C" void kernel_launch(void* const* d_in, const int* in_sizes, int n_in,
                              void* d_out, int out_size, void* d_ws, size_t ws_size,
                              hipStream_t stream)
{
    const float* x   = (const float*)d_in[0];
    const int*   ei  = (const int*)d_in[1];
    const float* Wl0 = (const float*)d_in[2];
    const float* bl0 = (const float*)d_in[3];
    const float* Wr0 = (const float*)d_in[4];
    const float* Wls = (const float*)d_in[5];
    const float* bls = (const float*)d_in[6];
    const float* Wrs = (const float*)d_in[7];
    const float* W1  = (const float*)d_in[8];
    const float* b1  = (const float*)d_in[9];
    const float* W2  = (const float*)d_in[10];
    const float* b2  = (const float*)d_in[11];
    const float* W3  = (const float*)d_in[12];
    const float* b3  = (const float*)d_in[13];

    const int n  = in_sizes[0] / 32;
    const int ne = in_sizes[1] / 2;
    const int* src = ei;
    const int* dst = ei + ne;
    const int nbuck = (n + BWID - 1) >> SH;

    // workspace (~33 MB, ws is ~268 MB per harness fill size)
    float*    acc0    = (float*)d_ws;                        // [n*16]
    float*    acc1    = acc0 + (size_t)n * 16;               // [n*16]
    unsigned* hlbA    = (unsigned*)(acc1 + (size_t)n * 16);  // [n*8]
    unsigned* hlbB    = hlbA + (size_t)n * 8;                // [n*8]
    int*      binned1 = (int*)(hlbB + (size_t)n * 8);        // [ne]
    int*      noff    = binned1 + (size_t)ne;                // [n+1]
    int*      bcnt    = noff + (n + 1);                      // [NBMAX]
    int*      bbase   = bcnt + NBMAX;                        // [NBMAX+1]
    int*      cursors = bbase + NBMAX + 1;                   // [NBMAX]
    unsigned* binned0 = (unsigned*)(cursors + NBMAX);        // [ne]

    const int nb = (n + 127) / 128;
    const int cb = (ne + CHUNK - 1) / CHUNK;

    // ---- build ----
    hipMemsetAsync(bcnt, 0, NBMAX * sizeof(int), stream);
    bucket_hist<<<cb, 256, 0, stream>>>(dst, bcnt, ne);
    bucket_scan<<<1, 1024, 0, stream>>>(bcnt, bbase, cursors, noff, nbuck, n, ne);
    bin_kernel<<<cb, 256, 0, stream>>>(src, dst, cursors, binned0, ne);
    node_sort<<<nbuck, 256, 0, stream>>>(binned0, bbase, binned1, noff, n);

    // ---- layers (hl ping-pong A/B; acc ping-pong 0/1) ----
    dense0<<<nb, 128, 0, stream>>>(x, Wl0, bl0, Wr0, hlbA, acc0, n);
    fused_agg_dense<<<nbuck, 256, 0, stream>>>(noff, binned1, hlbA, acc0,
        Wls + 0,   bls + 0,  Wrs + 0,   hlbB, acc1, n);
    fused_agg_dense<<<nbuck, 256, 0, stream>>>(noff, binned1, hlbB, acc1,
        Wls + 256, bls + 16, Wrs + 256, hlbA, acc0, n);
    fused_agg_dense<<<nbuck, 256, 0, stream>>>(noff, binned1, hlbA, acc0,
        Wls + 512, bls + 32, Wrs + 512, hlbB, acc1, n);
    fused_agg_mlp<<<nbuck, 256, 0, stream>>>(noff, binned1, hlbB, acc1,
        W1, b1, W2, b2, W3, b3, (float*)d_out, n);
}